// Round 4
// baseline (847.579 us; speedup 1.0000x reference)
//
#include <hip/hip_runtime.h>
#include <math.h>

#define HDIM 128

typedef _Float16 f16;
typedef unsigned short u16;
typedef __attribute__((ext_vector_type(2))) _Float16 f16x2;
typedef __attribute__((ext_vector_type(4))) _Float16 f16x4;
typedef __attribute__((ext_vector_type(8))) _Float16 f16x8;
typedef __attribute__((ext_vector_type(4))) float f32x4;

// ================= CSR build =================
// bucket-rank: counts per (dst, src>>12); folding buckets ascending at fill
// time yields approx src-sorted lists (free, small fetch win).
__global__ __launch_bounds__(256) void degrank_kernel(
    const int* __restrict__ edg, int* __restrict__ cnt,
    u16* __restrict__ rank, int E) {
  int e = blockIdx.x * 256 + threadIdx.x;
  if (e < E) {
    int src = edg[e];
    int dst = edg[E + e];
    rank[e] = (u16)atomicAdd(&cnt[dst * 16 + (src >> 12)], 1);
  }
}

// per-node: exclusive-scan the 16 bucket counters in place, emit total degree
__global__ __launch_bounds__(256) void nodescan_kernel(
    int* __restrict__ cnt, int* __restrict__ deg, int N) {
  int node = blockIdx.x * 256 + threadIdx.x;
  if (node >= N) return;
  int* c = cnt + node * 16;
  int s = 0;
  #pragma unroll
  for (int b = 0; b < 16; ++b) {
    int v = c[b];
    c[b] = s;
    s += v;
  }
  deg[node] = s;
}

__global__ __launch_bounds__(256) void scan_part_kernel(
    const int* __restrict__ deg, int* __restrict__ bsum, int n, int chunk) {
  __shared__ int red[256];
  const int b = blockIdx.x, t = threadIdx.x;
  const int begin = b * chunk;
  const int end = min(begin + chunk, n);
  int s = 0;
  for (int i = begin + t; i < end; i += 256) s += deg[i];
  red[t] = s;
  __syncthreads();
  for (int off = 128; off > 0; off >>= 1) {
    if (t < off) red[t] += red[t + off];
    __syncthreads();
  }
  if (t == 0) bsum[b] = red[0];
}

__global__ __launch_bounds__(256) void scan_top_kernel(
    const int* __restrict__ bsum, int* __restrict__ boff,
    int* __restrict__ offs, int n) {
  __shared__ int sh[256];
  const int t = threadIdx.x;
  int v = bsum[t];
  sh[t] = v;
  __syncthreads();
  for (int off = 1; off < 256; off <<= 1) {
    int add = (t >= off) ? sh[t - off] : 0;
    __syncthreads();
    sh[t] += add;
    __syncthreads();
  }
  boff[t] = sh[t] - v;
  if (t == 255) offs[n] = sh[255];
}

__global__ __launch_bounds__(256) void scan_fin_kernel(
    const int* __restrict__ deg, const int* __restrict__ boff,
    int* __restrict__ offs, int n, int chunk) {
  __shared__ int sh[256];
  const int b = blockIdx.x, t = threadIdx.x;
  const int idx = b * chunk + t;
  int v = (t < chunk && idx < n) ? deg[idx] : 0;
  sh[t] = v;
  __syncthreads();
  for (int off = 1; off < 256; off <<= 1) {
    int add = (t >= off) ? sh[t - off] : 0;
    __syncthreads();
    sh[t] += add;
    __syncthreads();
  }
  if (t < chunk && idx < n) offs[idx] = boff[b] + sh[t] - v;
}

// atomic-free fill: pos = offs[dst] + bucket_off[dst][src>>12] + rank[e]
__global__ __launch_bounds__(256) void fill_kernel(
    const int* __restrict__ edg, const int* __restrict__ offs,
    const int* __restrict__ cnt, const u16* __restrict__ rank,
    u16* __restrict__ csr_src, int E) {
  int i = blockIdx.x * 256 + threadIdx.x;
  int e0 = i * 4;
  if (e0 >= E) return;
  if (e0 + 4 <= E) {
    int4 s4 = *reinterpret_cast<const int4*>(edg + e0);
    int4 d4 = *reinterpret_cast<const int4*>(edg + E + e0);
    ushort4 r4 = *reinterpret_cast<const ushort4*>(rank + e0);
    csr_src[offs[d4.x] + cnt[d4.x * 16 + (s4.x >> 12)] + r4.x] = (u16)s4.x;
    csr_src[offs[d4.y] + cnt[d4.y * 16 + (s4.y >> 12)] + r4.y] = (u16)s4.y;
    csr_src[offs[d4.z] + cnt[d4.z * 16 + (s4.z >> 12)] + r4.z] = (u16)s4.z;
    csr_src[offs[d4.w] + cnt[d4.w * 16 + (s4.w >> 12)] + r4.w] = (u16)s4.w;
  } else {
    for (int e = e0; e < E; ++e) {
      int src = edg[e];
      int dst = edg[E + e];
      csr_src[offs[dst] + cnt[dst * 16 + (src >> 12)] + rank[e]] = (u16)src;
    }
  }
}

// ================= fp32 -> fp16 conversion (normal stores: gather tables
// want L2 residency) =================
__global__ __launch_bounds__(256) void convh_kernel(
    const float* __restrict__ s, f16* __restrict__ d, int n4) {
  int i = blockIdx.x * 256 + threadIdx.x;
  if (i < n4) {
    float4 v = reinterpret_cast<const float4*>(s)[i];
    f16x4 o;
    o[0] = (f16)v.x; o[1] = (f16)v.y; o[2] = (f16)v.z; o[3] = (f16)v.w;
    reinterpret_cast<f16x4*>(d)[i] = o;
  }
}

// ================= W transpose + fp16: WT[gate][n][k] =================
__global__ __launch_bounds__(256) void transw_kernel(
    const float* __restrict__ W, f16* __restrict__ WT) {
  __shared__ float sh[32][33];
  const int g = blockIdx.y;
  const int ti = blockIdx.x >> 2;
  const int tj = blockIdx.x & 3;
  const float* __restrict__ wp = W + (size_t)g * HDIM * HDIM;
  f16* __restrict__ op = WT + (size_t)g * HDIM * HDIM;
  const int t = threadIdx.x;
  #pragma unroll
  for (int it = 0; it < 4; ++it) {
    int elem = it * 256 + t;
    int r = elem >> 5, c = elem & 31;
    sh[r][c] = wp[(size_t)(ti * 32 + r) * HDIM + tj * 32 + c];
  }
  __syncthreads();
  #pragma unroll
  for (int it = 0; it < 4; ++it) {
    int elem = it * 256 + t;
    int cc = elem >> 5, rr = elem & 31;
    op[(size_t)(tj * 32 + cc) * HDIM + ti * 32 + rr] = (f16)sh[rr][cc];
  }
}

// ================= in-block gather: 64 rows of (self + neighbor sum) ========
// 256 threads = 16 groups x 16 lanes; each group owns rows {rr*16+grp},
// lane covers cols c..c+7 (f16x8 = one 256B row per group). 8 rows in
// flight per group -> 32 per wave (matches standalone pull MLP).
__device__ __forceinline__ void gather_rows(
    const u16* __restrict__ csr, const int* __restrict__ offs,
    const f16* __restrict__ tab, f16* __restrict__ As,
    int row0, int N, int t) {
  const int grp = t >> 4;
  const int c = (t & 15) << 3;
  #pragma unroll
  for (int rr = 0; rr < 4; ++rr) {
    const int r = rr * 16 + grp;
    const int node = row0 + r;
    float acc[8];
    #pragma unroll
    for (int q = 0; q < 8; ++q) acc[q] = 0.f;
    if (node < N) {
      f16x8 sv = *reinterpret_cast<const f16x8*>(tab + (size_t)node * HDIM + c);
      #pragma unroll
      for (int q = 0; q < 8; ++q) acc[q] = (float)sv[q];
      const int s = offs[node];
      const int e = offs[node + 1];
      int k = s;
      for (; k + 8 <= e; k += 8) {
        int j0 = csr[k];
        int j1 = csr[k + 1];
        int j2 = csr[k + 2];
        int j3 = csr[k + 3];
        int j4 = csr[k + 4];
        int j5 = csr[k + 5];
        int j6 = csr[k + 6];
        int j7 = csr[k + 7];
        f16x8 u0 = *reinterpret_cast<const f16x8*>(tab + (size_t)j0 * HDIM + c);
        f16x8 u1 = *reinterpret_cast<const f16x8*>(tab + (size_t)j1 * HDIM + c);
        f16x8 u2 = *reinterpret_cast<const f16x8*>(tab + (size_t)j2 * HDIM + c);
        f16x8 u3 = *reinterpret_cast<const f16x8*>(tab + (size_t)j3 * HDIM + c);
        f16x8 u4 = *reinterpret_cast<const f16x8*>(tab + (size_t)j4 * HDIM + c);
        f16x8 u5 = *reinterpret_cast<const f16x8*>(tab + (size_t)j5 * HDIM + c);
        f16x8 u6 = *reinterpret_cast<const f16x8*>(tab + (size_t)j6 * HDIM + c);
        f16x8 u7 = *reinterpret_cast<const f16x8*>(tab + (size_t)j7 * HDIM + c);
        #pragma unroll
        for (int q = 0; q < 8; ++q)
          acc[q] += (((float)u0[q] + (float)u1[q]) + ((float)u2[q] + (float)u3[q])) +
                    (((float)u4[q] + (float)u5[q]) + ((float)u6[q] + (float)u7[q]));
      }
      for (; k < e; ++k) {
        f16x8 u = *reinterpret_cast<const f16x8*>(tab + (size_t)csr[k] * HDIM + c);
        #pragma unroll
        for (int q = 0; q < 8; ++q) acc[q] += (float)u[q];
      }
    }
    f16x8 o;
    #pragma unroll
    for (int q = 0; q < 8; ++q) o[q] = (f16)acc[q];
    *reinterpret_cast<f16x8*>(&As[r * 136 + c]) = o;
  }
}

__device__ __forceinline__ void mfma_tile(
    const f16* As, const f16* Ws, int wr, int wc, int ln15, int quad,
    f32x4 (&acc)[2][4]) {
  #pragma unroll
  for (int s = 0; s < 4; ++s) {
    f16x8 a0 = *reinterpret_cast<const f16x8*>(
        &As[(wr * 32 + ln15) * 136 + s * 32 + quad * 8]);
    f16x8 a1 = *reinterpret_cast<const f16x8*>(
        &As[(wr * 32 + 16 + ln15) * 136 + s * 32 + quad * 8]);
    #pragma unroll
    for (int ni = 0; ni < 4; ++ni) {
      f16x8 bf = *reinterpret_cast<const f16x8*>(
          &Ws[(wc * 64 + ni * 16 + ln15) * 136 + s * 32 + quad * 8]);
      acc[0][ni] = __builtin_amdgcn_mfma_f32_16x16x32_f16(a0, bf, acc[0][ni], 0, 0, 0);
      acc[1][ni] = __builtin_amdgcn_mfma_f32_16x16x32_f16(a1, bf, acc[1][ni], 0, 0, 0);
    }
  }
}

// ============ fused gather + gate GEMM (z, r, h-partial in one pass) ========
__global__ __launch_bounds__(256, 3) void gemm3_kernel(
    const u16* __restrict__ csr_src, const int* __restrict__ offs,
    const f16* __restrict__ xb, const f16* __restrict__ hb,
    const f16* __restrict__ WT, const float* __restrict__ b,
    f16* __restrict__ zb, f16* __restrict__ cb,
    float* __restrict__ hpre, int N) {
  __shared__ f16 As[64 * 136];
  __shared__ f16 Ws[128 * 136];
  const int t = threadIdx.x;
  const int w = t >> 6, wr = w >> 1, wc = w & 1;
  const int lane = t & 63, ln15 = lane & 15, quad = lane >> 4;
  const int row0 = blockIdx.x * 64;
  f32x4 accZ[2][4], accR[2][4], accH[2][4];
  #pragma unroll
  for (int i = 0; i < 2; ++i)
    #pragma unroll
    for (int j = 0; j < 4; ++j) {
      accZ[i][j] = (f32x4){0.f, 0.f, 0.f, 0.f};
      accR[i][j] = (f32x4){0.f, 0.f, 0.f, 0.f};
      accH[i][j] = (f32x4){0.f, 0.f, 0.f, 0.f};
    }

  // ---- gather x-aggregate into As ----
  gather_rows(csr_src, offs, xb, As, row0, N, t);
  #pragma unroll
  for (int g = 0; g < 3; ++g) {          // gates 0,2,4 against x-aggregate
    const f16* __restrict__ wp = WT + (size_t)(g * 2) * HDIM * HDIM;
    __syncthreads();                     // As ready / Ws free
    #pragma unroll
    for (int i = 0; i < 8; ++i) {
      int flat = i * 256 + t;
      int n = flat >> 4;
      int o = (flat & 15) * 8;
      *reinterpret_cast<f16x8*>(&Ws[n * 136 + o]) =
          *reinterpret_cast<const f16x8*>(wp + (size_t)n * HDIM + o);
    }
    __syncthreads();
    if (g == 0) mfma_tile(As, Ws, wr, wc, ln15, quad, accZ);
    else if (g == 1) mfma_tile(As, Ws, wr, wc, ln15, quad, accR);
    else mfma_tile(As, Ws, wr, wc, ln15, quad, accH);
  }
  __syncthreads();                       // all reads of As done
  // ---- gather h-aggregate into As ----
  gather_rows(csr_src, offs, hb, As, row0, N, t);
  #pragma unroll
  for (int g = 0; g < 2; ++g) {          // gates 1,3 against h-aggregate
    const f16* __restrict__ wp = WT + (size_t)(g * 2 + 1) * HDIM * HDIM;
    __syncthreads();
    #pragma unroll
    for (int i = 0; i < 8; ++i) {
      int flat = i * 256 + t;
      int n = flat >> 4;
      int o = (flat & 15) * 8;
      *reinterpret_cast<f16x8*>(&Ws[n * 136 + o]) =
          *reinterpret_cast<const f16x8*>(wp + (size_t)n * HDIM + o);
    }
    __syncthreads();
    if (g == 0) mfma_tile(As, Ws, wr, wc, ln15, quad, accZ);
    else mfma_tile(As, Ws, wr, wc, ln15, quad, accR);
  }

  // ---- epilogue: zpre, c=sigmoid(r)*h, hpre ----
  #pragma unroll
  for (int ni = 0; ni < 4; ++ni) {
    const int col = wc * 64 + ni * 16 + ln15;
    float bz = b[0 * HDIM + col] + b[1 * HDIM + col];
    float br = b[2 * HDIM + col] + b[3 * HDIM + col];
    float bh = b[4 * HDIM + col];
    #pragma unroll
    for (int mi = 0; mi < 2; ++mi) {
      #pragma unroll
      for (int r = 0; r < 4; ++r) {
        int row = row0 + wr * 32 + mi * 16 + quad * 4 + r;
        if (row >= N) continue;
        size_t idx = (size_t)row * HDIM + col;
        zb[idx] = (f16)(accZ[mi][ni][r] + bz);
        float rv = accR[mi][ni][r] + br;
        float rg = 1.f / (1.f + expf(-rv));
        cb[idx] = (f16)(rg * (float)hb[idx]);
        hpre[idx] = accH[mi][ni][r] + bh;
      }
    }
  }
}

// ============ fused gather + final GEMM + GRU combine =======================
__global__ __launch_bounds__(256, 3) void gemm_final_kernel(
    const u16* __restrict__ csr_src, const int* __restrict__ offs,
    const f16* __restrict__ cb, const f16* __restrict__ WT5,
    const float* __restrict__ b5, const f16* __restrict__ zb,
    const float* __restrict__ hi, float* __restrict__ outi,
    f16* __restrict__ xb, int N) {
  __shared__ f16 As[64 * 136];
  __shared__ f16 Ws[128 * 136];
  const int t = threadIdx.x;
  const int w = t >> 6, wr = w >> 1, wc = w & 1;
  const int lane = t & 63, ln15 = lane & 15, quad = lane >> 4;
  const int row0 = blockIdx.x * 64;
  f32x4 acc[2][4];
  #pragma unroll
  for (int i = 0; i < 2; ++i)
    #pragma unroll
    for (int j = 0; j < 4; ++j) acc[i][j] = (f32x4){0.f, 0.f, 0.f, 0.f};

  // gather c-aggregate into As; stage W5 concurrently-in-program-order
  gather_rows(csr_src, offs, cb, As, row0, N, t);
  #pragma unroll
  for (int i = 0; i < 8; ++i) {
    int flat = i * 256 + t;
    int n = flat >> 4;
    int o = (flat & 15) * 8;
    *reinterpret_cast<f16x8*>(&Ws[n * 136 + o]) =
        *reinterpret_cast<const f16x8*>(WT5 + (size_t)n * HDIM + o);
  }
  __syncthreads();
  mfma_tile(As, Ws, wr, wc, ln15, quad, acc);

  #pragma unroll
  for (int ni = 0; ni < 4; ++ni) {
    const int col = wc * 64 + ni * 16 + ln15;
    float bias = b5[col];
    #pragma unroll
    for (int mi = 0; mi < 2; ++mi) {
      #pragma unroll
      for (int r = 0; r < 4; ++r) {
        int row = row0 + wr * 32 + mi * 16 + quad * 4 + r;
        if (row >= N) continue;
        size_t idx = (size_t)row * HDIM + col;
        float v = acc[mi][ni][r] + bias + outi[idx];  // + hpre
        float ht = tanhf(v);
        float z = 1.f / (1.f + expf(-(float)zb[idx]));
        float o = z * hi[idx] + (1.f - z) * ht;
        outi[idx] = o;
        xb[idx] = (f16)o;
      }
    }
  }
}

extern "C" void kernel_launch(void* const* d_in, const int* in_sizes, int n_in,
                              void* d_out, int out_size, void* d_ws, size_t ws_size,
                              hipStream_t stream) {
  const float* inp = (const float*)d_in[0];
  const int*   edg = (const int*)d_in[1];
  const float* h   = (const float*)d_in[2];
  const float* W   = (const float*)d_in[3];
  const float* b   = (const float*)d_in[4];
  float* out = (float*)d_out;

  const int NH = in_sizes[0];      // N*H
  const int N  = NH / HDIM;
  const int E  = in_sizes[1] / 2;
  const int L  = in_sizes[2] / NH;

  f16* zbuf = (f16*)d_ws;               // zpre
  f16* cbuf = zbuf + (size_t)NH;        // sigmoid(r)*h  (gather table)
  f16* xbuf = cbuf + (size_t)NH;        // x f16 (gather table)
  f16* hbuf = xbuf + (size_t)NH;        // h f16, BOTH layers (gather tables)
  f16* WT   = hbuf + (size_t)L * NH;    // L*6*H*H transposed f16 weights
  int* deg     = (int*)(WT + (size_t)L * 6 * HDIM * HDIM);
  int* offs    = deg + N;               // N+1
  int* bsum    = offs + (N + 1);        // 256
  int* boff    = bsum + 256;            // 256
  u16* rank    = (u16*)(boff + 256);    // E
  u16* csr_src = rank + (size_t)E;      // E
  // bucket counters: N*16 ints, only live during CSR build -> overlay on
  // zbuf+cbuf region (2*NH f16 = 4*NH bytes >= 64*N bytes)
  int* cnt     = (int*)zbuf;

  const int eblocks = (E + 255) / 256;
  const int fblocks = (E + 1023) / 1024;
  const int nsblocks = (N + 255) / 256;
  const int n4 = NH / 4;
  const int cvblocks = (n4 + 255) / 256;
  const int hn4 = (L * NH) / 4;
  const int hvblocks = (hn4 + 255) / 256;
  const int rowblocks = (N + 63) / 64;
  const int chunk = (N + 255) / 256;    // <=256 requires N<=65536

  // ---- one-time per call: CSR build (approx src-sorted), transpose, f16 ----
  hipMemsetAsync(cnt, 0, (size_t)N * 16 * sizeof(int), stream);
  hipLaunchKernelGGL(degrank_kernel, dim3(eblocks), dim3(256), 0, stream,
                     edg, cnt, rank, E);
  hipLaunchKernelGGL(nodescan_kernel, dim3(nsblocks), dim3(256), 0, stream,
                     cnt, deg, N);
  hipLaunchKernelGGL(scan_part_kernel, dim3(256), dim3(256), 0, stream,
                     deg, bsum, N, chunk);
  hipLaunchKernelGGL(scan_top_kernel, dim3(1), dim3(256), 0, stream,
                     bsum, boff, offs, N);
  hipLaunchKernelGGL(scan_fin_kernel, dim3(256), dim3(256), 0, stream,
                     deg, boff, offs, N, chunk);
  hipLaunchKernelGGL(fill_kernel, dim3(fblocks), dim3(256), 0, stream,
                     edg, offs, cnt, rank, csr_src, E);
  hipLaunchKernelGGL(transw_kernel, dim3(16, L * 6), dim3(256), 0, stream,
                     W, WT);
  hipLaunchKernelGGL(convh_kernel, dim3(cvblocks), dim3(256), 0, stream,
                     inp, xbuf, n4);
  hipLaunchKernelGGL(convh_kernel, dim3(hvblocks), dim3(256), 0, stream,
                     h, hbuf, hn4);     // both layers' h in one dispatch

  for (int i = 0; i < L; ++i) {
    const float* hi = h + (size_t)i * NH;
    const f16* hbi = hbuf + (size_t)i * NH;
    const f16* WTi = WT + (size_t)i * 6 * HDIM * HDIM;
    const float* bi = b + (size_t)i * 6 * HDIM;
    float* outi = out + (size_t)i * NH;

    hipLaunchKernelGGL(gemm3_kernel, dim3(rowblocks), dim3(256), 0, stream,
                       csr_src, offs, xbuf, hbi, WTi, bi, zbuf, cbuf, outi, N);
    hipLaunchKernelGGL(gemm_final_kernel, dim3(rowblocks), dim3(256), 0, stream,
                       csr_src, offs, cbuf, WTi + (size_t)5 * HDIM * HDIM,
                       bi + 5 * HDIM, zbuf, hi, outi, xbuf, N);
  }
}

// Round 5
// 799.641 us; speedup vs baseline: 1.0599x; 1.0599x over previous
//
#include <hip/hip_runtime.h>
#include <math.h>

#define HDIM 128

typedef _Float16 f16;
typedef unsigned short u16;
typedef __attribute__((ext_vector_type(4))) _Float16 f16x4;
typedef __attribute__((ext_vector_type(8))) _Float16 f16x8;
typedef __attribute__((ext_vector_type(4))) float f32x4;

// ================= CSR build =================
// bucket-rank: counts per (dst, src>>12); folding buckets ascending at fill
// time yields approx src-sorted lists (free, small fetch win).
__global__ __launch_bounds__(256) void degrank_kernel(
    const int* __restrict__ edg, int* __restrict__ cnt,
    u16* __restrict__ rank, int E) {
  int e = blockIdx.x * 256 + threadIdx.x;
  if (e < E) {
    int src = edg[e];
    int dst = edg[E + e];
    rank[e] = (u16)atomicAdd(&cnt[dst * 16 + (src >> 12)], 1);
  }
}

__global__ __launch_bounds__(256) void nodescan_kernel(
    int* __restrict__ cnt, int* __restrict__ deg, int N) {
  int node = blockIdx.x * 256 + threadIdx.x;
  if (node >= N) return;
  int* c = cnt + node * 16;
  int s = 0;
  #pragma unroll
  for (int b = 0; b < 16; ++b) {
    int v = c[b];
    c[b] = s;
    s += v;
  }
  deg[node] = s;
}

__global__ __launch_bounds__(256) void scan_part_kernel(
    const int* __restrict__ deg, int* __restrict__ bsum, int n, int chunk) {
  __shared__ int red[256];
  const int b = blockIdx.x, t = threadIdx.x;
  const int begin = b * chunk;
  const int end = min(begin + chunk, n);
  int s = 0;
  for (int i = begin + t; i < end; i += 256) s += deg[i];
  red[t] = s;
  __syncthreads();
  for (int off = 128; off > 0; off >>= 1) {
    if (t < off) red[t] += red[t + off];
    __syncthreads();
  }
  if (t == 0) bsum[b] = red[0];
}

__global__ __launch_bounds__(256) void scan_top_kernel(
    const int* __restrict__ bsum, int* __restrict__ boff,
    int* __restrict__ offs, int n) {
  __shared__ int sh[256];
  const int t = threadIdx.x;
  int v = bsum[t];
  sh[t] = v;
  __syncthreads();
  for (int off = 1; off < 256; off <<= 1) {
    int add = (t >= off) ? sh[t - off] : 0;
    __syncthreads();
    sh[t] += add;
    __syncthreads();
  }
  boff[t] = sh[t] - v;
  if (t == 255) offs[n] = sh[255];
}

__global__ __launch_bounds__(256) void scan_fin_kernel(
    const int* __restrict__ deg, const int* __restrict__ boff,
    int* __restrict__ offs, int n, int chunk) {
  __shared__ int sh[256];
  const int b = blockIdx.x, t = threadIdx.x;
  const int idx = b * chunk + t;
  int v = (t < chunk && idx < n) ? deg[idx] : 0;
  sh[t] = v;
  __syncthreads();
  for (int off = 1; off < 256; off <<= 1) {
    int add = (t >= off) ? sh[t - off] : 0;
    __syncthreads();
    sh[t] += add;
    __syncthreads();
  }
  if (t < chunk && idx < n) offs[idx] = boff[b] + sh[t] - v;
}

__global__ __launch_bounds__(256) void fill_kernel(
    const int* __restrict__ edg, const int* __restrict__ offs,
    const int* __restrict__ cnt, const u16* __restrict__ rank,
    u16* __restrict__ csr_src, int E) {
  int i = blockIdx.x * 256 + threadIdx.x;
  int e0 = i * 4;
  if (e0 >= E) return;
  if (e0 + 4 <= E) {
    int4 s4 = *reinterpret_cast<const int4*>(edg + e0);
    int4 d4 = *reinterpret_cast<const int4*>(edg + E + e0);
    ushort4 r4 = *reinterpret_cast<const ushort4*>(rank + e0);
    csr_src[offs[d4.x] + cnt[d4.x * 16 + (s4.x >> 12)] + r4.x] = (u16)s4.x;
    csr_src[offs[d4.y] + cnt[d4.y * 16 + (s4.y >> 12)] + r4.y] = (u16)s4.y;
    csr_src[offs[d4.z] + cnt[d4.z * 16 + (s4.z >> 12)] + r4.z] = (u16)s4.z;
    csr_src[offs[d4.w] + cnt[d4.w * 16 + (s4.w >> 12)] + r4.w] = (u16)s4.w;
  } else {
    for (int e = e0; e < E; ++e) {
      int src = edg[e];
      int dst = edg[E + e];
      csr_src[offs[dst] + cnt[dst * 16 + (src >> 12)] + rank[e]] = (u16)src;
    }
  }
}

// ===== fp32 [n][128] -> blocked fp16 [8][SN][16] (slice s = cols 16s..16s+15)
// 8 consecutive threads cover one node's 512B row -> coalesced reads.
__global__ __launch_bounds__(256) void convb_kernel(
    const float* __restrict__ src, f16* __restrict__ dst, int n, int SN) {
  const int t = threadIdx.x;
  const int nloc = t >> 3;
  const int sl = t & 7;
  const int node = blockIdx.x * 32 + nloc;
  if (node >= n) return;
  const float* sp = src + (size_t)node * HDIM + sl * 16;
  f16* dp = dst + ((size_t)sl * SN + node) * 16;
  float4 v0 = *reinterpret_cast<const float4*>(sp + 0);
  float4 v1 = *reinterpret_cast<const float4*>(sp + 4);
  float4 v2 = *reinterpret_cast<const float4*>(sp + 8);
  float4 v3 = *reinterpret_cast<const float4*>(sp + 12);
  f16x8 o0, o1;
  o0[0]=(f16)v0.x; o0[1]=(f16)v0.y; o0[2]=(f16)v0.z; o0[3]=(f16)v0.w;
  o0[4]=(f16)v1.x; o0[5]=(f16)v1.y; o0[6]=(f16)v1.z; o0[7]=(f16)v1.w;
  o1[0]=(f16)v2.x; o1[1]=(f16)v2.y; o1[2]=(f16)v2.z; o1[3]=(f16)v2.w;
  o1[4]=(f16)v3.x; o1[5]=(f16)v3.y; o1[6]=(f16)v3.z; o1[7]=(f16)v3.w;
  *reinterpret_cast<f16x8*>(dp) = o0;
  *reinterpret_cast<f16x8*>(dp + 8) = o1;
}

// ================= W transpose + fp16: WT[gate][n][k] =================
__global__ __launch_bounds__(256) void transw_kernel(
    const float* __restrict__ W, f16* __restrict__ WT) {
  __shared__ float sh[32][33];
  const int g = blockIdx.y;
  const int ti = blockIdx.x >> 2;
  const int tj = blockIdx.x & 3;
  const float* __restrict__ wp = W + (size_t)g * HDIM * HDIM;
  f16* __restrict__ op = WT + (size_t)g * HDIM * HDIM;
  const int t = threadIdx.x;
  #pragma unroll
  for (int it = 0; it < 4; ++it) {
    int elem = it * 256 + t;
    int r = elem >> 5, c = elem & 31;
    sh[r][c] = wp[(size_t)(ti * 32 + r) * HDIM + tj * 32 + c];
  }
  __syncthreads();
  #pragma unroll
  for (int it = 0; it < 4; ++it) {
    int elem = it * 256 + t;
    int cc = elem >> 5, rr = elem & 31;
    op[(size_t)(tj * 32 + cc) * HDIM + ti * 32 + rr] = (f16)sh[rr][cc];
  }
}

// ================= XCD-sliced pull aggregation =================
// slice = blockIdx & 7 -> with round-robin blockIdx->XCD dispatch, every
// block resident on XCD k gathers ONLY slice k (1.6 MB/table) -> L2-resident.
// Block: threads 0-127 x-table, 128-255 h-table; 2 lanes per node (f16x8 each).
__global__ __launch_bounds__(256) void pull2_kernel(
    const u16* __restrict__ csr_src, const int* __restrict__ offs,
    const f16* __restrict__ xb, const f16* __restrict__ hbl,
    f16* __restrict__ A, f16* __restrict__ Bh, int N, int hSN) {
  const int sl = blockIdx.x & 7;
  const int node = (blockIdx.x >> 3) * 64 + ((threadIdx.x & 127) >> 1);
  if (node >= N) return;
  const int half = threadIdx.x >> 7;
  const int c8 = (threadIdx.x & 1) << 3;
  const f16* __restrict__ tab =
      half ? hbl + (size_t)sl * hSN * 16 : xb + (size_t)sl * N * 16;
  f16* __restrict__ dst = (half ? Bh : A) + (size_t)sl * N * 16;
  const int s = offs[node];
  const int e = offs[node + 1];
  float acc[8];
  f16x8 sv = *reinterpret_cast<const f16x8*>(tab + (size_t)node * 16 + c8);
  #pragma unroll
  for (int q = 0; q < 8; ++q) acc[q] = (float)sv[q];
  int k = s;
  for (; k + 8 <= e; k += 8) {
    int j0 = csr_src[k];
    int j1 = csr_src[k + 1];
    int j2 = csr_src[k + 2];
    int j3 = csr_src[k + 3];
    int j4 = csr_src[k + 4];
    int j5 = csr_src[k + 5];
    int j6 = csr_src[k + 6];
    int j7 = csr_src[k + 7];
    f16x8 u0 = *reinterpret_cast<const f16x8*>(tab + (size_t)j0 * 16 + c8);
    f16x8 u1 = *reinterpret_cast<const f16x8*>(tab + (size_t)j1 * 16 + c8);
    f16x8 u2 = *reinterpret_cast<const f16x8*>(tab + (size_t)j2 * 16 + c8);
    f16x8 u3 = *reinterpret_cast<const f16x8*>(tab + (size_t)j3 * 16 + c8);
    f16x8 u4 = *reinterpret_cast<const f16x8*>(tab + (size_t)j4 * 16 + c8);
    f16x8 u5 = *reinterpret_cast<const f16x8*>(tab + (size_t)j5 * 16 + c8);
    f16x8 u6 = *reinterpret_cast<const f16x8*>(tab + (size_t)j6 * 16 + c8);
    f16x8 u7 = *reinterpret_cast<const f16x8*>(tab + (size_t)j7 * 16 + c8);
    #pragma unroll
    for (int q = 0; q < 8; ++q)
      acc[q] += (((float)u0[q] + (float)u1[q]) + ((float)u2[q] + (float)u3[q])) +
                (((float)u4[q] + (float)u5[q]) + ((float)u6[q] + (float)u7[q]));
  }
  for (; k < e; ++k) {
    f16x8 u = *reinterpret_cast<const f16x8*>(tab + (size_t)csr_src[k] * 16 + c8);
    #pragma unroll
    for (int q = 0; q < 8; ++q) acc[q] += (float)u[q];
  }
  f16x8 o;
  #pragma unroll
  for (int q = 0; q < 8; ++q) o[q] = (f16)acc[q];
  *reinterpret_cast<f16x8*>(dst + (size_t)node * 16 + c8) = o;
}

// single-table sliced pull: 128 nodes per block, 2 lanes per node
__global__ __launch_bounds__(256) void pull1_kernel(
    const u16* __restrict__ csr_src, const int* __restrict__ offs,
    const f16* __restrict__ cb, f16* __restrict__ Ctot, int N) {
  const int sl = blockIdx.x & 7;
  const int node = (blockIdx.x >> 3) * 128 + (threadIdx.x >> 1);
  if (node >= N) return;
  const int c8 = (threadIdx.x & 1) << 3;
  const f16* __restrict__ tab = cb + (size_t)sl * N * 16;
  f16* __restrict__ dst = Ctot + (size_t)sl * N * 16;
  const int s = offs[node];
  const int e = offs[node + 1];
  float acc[8];
  f16x8 sv = *reinterpret_cast<const f16x8*>(tab + (size_t)node * 16 + c8);
  #pragma unroll
  for (int q = 0; q < 8; ++q) acc[q] = (float)sv[q];
  int k = s;
  for (; k + 8 <= e; k += 8) {
    int j0 = csr_src[k];
    int j1 = csr_src[k + 1];
    int j2 = csr_src[k + 2];
    int j3 = csr_src[k + 3];
    int j4 = csr_src[k + 4];
    int j5 = csr_src[k + 5];
    int j6 = csr_src[k + 6];
    int j7 = csr_src[k + 7];
    f16x8 u0 = *reinterpret_cast<const f16x8*>(tab + (size_t)j0 * 16 + c8);
    f16x8 u1 = *reinterpret_cast<const f16x8*>(tab + (size_t)j1 * 16 + c8);
    f16x8 u2 = *reinterpret_cast<const f16x8*>(tab + (size_t)j2 * 16 + c8);
    f16x8 u3 = *reinterpret_cast<const f16x8*>(tab + (size_t)j3 * 16 + c8);
    f16x8 u4 = *reinterpret_cast<const f16x8*>(tab + (size_t)j4 * 16 + c8);
    f16x8 u5 = *reinterpret_cast<const f16x8*>(tab + (size_t)j5 * 16 + c8);
    f16x8 u6 = *reinterpret_cast<const f16x8*>(tab + (size_t)j6 * 16 + c8);
    f16x8 u7 = *reinterpret_cast<const f16x8*>(tab + (size_t)j7 * 16 + c8);
    #pragma unroll
    for (int q = 0; q < 8; ++q)
      acc[q] += (((float)u0[q] + (float)u1[q]) + ((float)u2[q] + (float)u3[q])) +
                (((float)u4[q] + (float)u5[q]) + ((float)u6[q] + (float)u7[q]));
  }
  for (; k < e; ++k) {
    f16x8 u = *reinterpret_cast<const f16x8*>(tab + (size_t)csr_src[k] * 16 + c8);
    #pragma unroll
    for (int q = 0; q < 8; ++q) acc[q] += (float)u[q];
  }
  f16x8 o;
  #pragma unroll
  for (int q = 0; q < 8; ++q) o[q] = (f16)acc[q];
  *reinterpret_cast<f16x8*>(dst + (size_t)node * 16 + c8) = o;
}

// ========== LDS staging from blocked [8][SN][16] layout ==========
__device__ __forceinline__ void stage_blocked(
    const f16* __restrict__ src, f16* __restrict__ As,
    int row0, int N, int SN, int t) {
  #pragma unroll
  for (int i = 0; i < 2; ++i) {
    int u = i * 256 + t;       // 512 units: (slice, row)
    int sl = u >> 6;
    int r = u & 63;
    int row = row0 + r;
    f16x8 v0{}, v1{};
    if (row < N) {
      const f16* p = src + ((size_t)sl * SN + row) * 16;
      v0 = *reinterpret_cast<const f16x8*>(p);
      v1 = *reinterpret_cast<const f16x8*>(p + 8);
    }
    *reinterpret_cast<f16x8*>(&As[r * 136 + sl * 16]) = v0;
    *reinterpret_cast<f16x8*>(&As[r * 136 + sl * 16 + 8]) = v1;
  }
}

__device__ __forceinline__ void mfma_tile(
    const f16* As, const f16* Ws, int wr, int wc, int ln15, int quad,
    f32x4 (&acc)[2][4]) {
  #pragma unroll
  for (int s = 0; s < 4; ++s) {
    f16x8 a0 = *reinterpret_cast<const f16x8*>(
        &As[(wr * 32 + ln15) * 136 + s * 32 + quad * 8]);
    f16x8 a1 = *reinterpret_cast<const f16x8*>(
        &As[(wr * 32 + 16 + ln15) * 136 + s * 32 + quad * 8]);
    #pragma unroll
    for (int ni = 0; ni < 4; ++ni) {
      f16x8 bf = *reinterpret_cast<const f16x8*>(
          &Ws[(wc * 64 + ni * 16 + ln15) * 136 + s * 32 + quad * 8]);
      acc[0][ni] = __builtin_amdgcn_mfma_f32_16x16x32_f16(a0, bf, acc[0][ni], 0, 0, 0);
      acc[1][ni] = __builtin_amdgcn_mfma_f32_16x16x32_f16(a1, bf, acc[1][ni], 0, 0, 0);
    }
  }
}

// ============ fused gate GEMM (z, r, h-partial in one pass) ========
__global__ __launch_bounds__(256, 3) void gemm3_kernel(
    const f16* __restrict__ A, const f16* __restrict__ Bh,
    const f16* __restrict__ WT, const float* __restrict__ b,
    const f16* __restrict__ hbl, f16* __restrict__ zb,
    f16* __restrict__ cb, float* __restrict__ hpre, int N, int hSN) {
  __shared__ f16 As[64 * 136];
  __shared__ f16 Ws[128 * 136];
  const int t = threadIdx.x;
  const int w = t >> 6, wr = w >> 1, wc = w & 1;
  const int lane = t & 63, ln15 = lane & 15, quad = lane >> 4;
  const int row0 = blockIdx.x * 64;
  f32x4 accZ[2][4], accR[2][4], accH[2][4];
  #pragma unroll
  for (int i = 0; i < 2; ++i)
    #pragma unroll
    for (int j = 0; j < 4; ++j) {
      accZ[i][j] = (f32x4){0.f, 0.f, 0.f, 0.f};
      accR[i][j] = (f32x4){0.f, 0.f, 0.f, 0.f};
      accH[i][j] = (f32x4){0.f, 0.f, 0.f, 0.f};
    }

  stage_blocked(A, As, row0, N, N, t);
  #pragma unroll
  for (int g = 0; g < 3; ++g) {          // gates 0,2,4 vs x-aggregate
    const f16* __restrict__ wp = WT + (size_t)(g * 2) * HDIM * HDIM;
    __syncthreads();
    #pragma unroll
    for (int i = 0; i < 8; ++i) {
      int flat = i * 256 + t;
      int n = flat >> 4;
      int o = (flat & 15) * 8;
      *reinterpret_cast<f16x8*>(&Ws[n * 136 + o]) =
          *reinterpret_cast<const f16x8*>(wp + (size_t)n * HDIM + o);
    }
    __syncthreads();
    if (g == 0) mfma_tile(As, Ws, wr, wc, ln15, quad, accZ);
    else if (g == 1) mfma_tile(As, Ws, wr, wc, ln15, quad, accR);
    else mfma_tile(As, Ws, wr, wc, ln15, quad, accH);
  }
  __syncthreads();
  stage_blocked(Bh, As, row0, N, N, t);
  #pragma unroll
  for (int g = 0; g < 2; ++g) {          // gates 1,3 vs h-aggregate
    const f16* __restrict__ wp = WT + (size_t)(g * 2 + 1) * HDIM * HDIM;
    __syncthreads();
    #pragma unroll
    for (int i = 0; i < 8; ++i) {
      int flat = i * 256 + t;
      int n = flat >> 4;
      int o = (flat & 15) * 8;
      *reinterpret_cast<f16x8*>(&Ws[n * 136 + o]) =
          *reinterpret_cast<const f16x8*>(wp + (size_t)n * HDIM + o);
    }
    __syncthreads();
    if (g == 0) mfma_tile(As, Ws, wr, wc, ln15, quad, accZ);
    else mfma_tile(As, Ws, wr, wc, ln15, quad, accR);
  }

  // ---- epilogue: zpre (linear), c=sigmoid(r)*h (blocked), hpre (linear) ----
  #pragma unroll
  for (int ni = 0; ni < 4; ++ni) {
    const int col = wc * 64 + ni * 16 + ln15;
    const int slc = wc * 4 + ni;         // col >> 4
    float bz = b[0 * HDIM + col] + b[1 * HDIM + col];
    float br = b[2 * HDIM + col] + b[3 * HDIM + col];
    float bh = b[4 * HDIM + col];
    #pragma unroll
    for (int mi = 0; mi < 2; ++mi) {
      #pragma unroll
      for (int r = 0; r < 4; ++r) {
        int row = row0 + wr * 32 + mi * 16 + quad * 4 + r;
        if (row >= N) continue;
        size_t idx = (size_t)row * HDIM + col;
        size_t bidx = ((size_t)slc * N + row) * 16 + ln15;
        zb[idx] = (f16)(accZ[mi][ni][r] + bz);
        float rv = accR[mi][ni][r] + br;
        float rg = 1.f / (1.f + expf(-rv));
        float hv = (float)hbl[((size_t)slc * hSN + row) * 16 + ln15];
        cb[bidx] = (f16)(rg * hv);
        hpre[idx] = accH[mi][ni][r] + bh;
      }
    }
  }
}

// ============ final GEMM + GRU combine =======================
__global__ __launch_bounds__(256, 3) void gemm_final_kernel(
    const f16* __restrict__ Ctot, const f16* __restrict__ WT5,
    const float* __restrict__ b5, const f16* __restrict__ zb,
    const float* __restrict__ hi, float* __restrict__ outi,
    f16* __restrict__ xb, int N) {
  __shared__ f16 As[64 * 136];
  __shared__ f16 Ws[128 * 136];
  const int t = threadIdx.x;
  const int w = t >> 6, wr = w >> 1, wc = w & 1;
  const int lane = t & 63, ln15 = lane & 15, quad = lane >> 4;
  const int row0 = blockIdx.x * 64;
  f32x4 acc[2][4];
  #pragma unroll
  for (int i = 0; i < 2; ++i)
    #pragma unroll
    for (int j = 0; j < 4; ++j) acc[i][j] = (f32x4){0.f, 0.f, 0.f, 0.f};

  stage_blocked(Ctot, As, row0, N, N, t);
  #pragma unroll
  for (int i = 0; i < 8; ++i) {
    int flat = i * 256 + t;
    int n = flat >> 4;
    int o = (flat & 15) * 8;
    *reinterpret_cast<f16x8*>(&Ws[n * 136 + o]) =
        *reinterpret_cast<const f16x8*>(WT5 + (size_t)n * HDIM + o);
  }
  __syncthreads();
  mfma_tile(As, Ws, wr, wc, ln15, quad, acc);

  #pragma unroll
  for (int ni = 0; ni < 4; ++ni) {
    const int col = wc * 64 + ni * 16 + ln15;
    const int slc = wc * 4 + ni;
    float bias = b5[col];
    #pragma unroll
    for (int mi = 0; mi < 2; ++mi) {
      #pragma unroll
      for (int r = 0; r < 4; ++r) {
        int row = row0 + wr * 32 + mi * 16 + quad * 4 + r;
        if (row >= N) continue;
        size_t idx = (size_t)row * HDIM + col;
        float v = acc[mi][ni][r] + bias + outi[idx];  // + hpre
        float ht = tanhf(v);
        float z = 1.f / (1.f + expf(-(float)zb[idx]));
        float o = z * hi[idx] + (1.f - z) * ht;
        outi[idx] = o;
        xb[((size_t)slc * N + row) * 16 + ln15] = (f16)o;  // blocked x table
      }
    }
  }
}

extern "C" void kernel_launch(void* const* d_in, const int* in_sizes, int n_in,
                              void* d_out, int out_size, void* d_ws, size_t ws_size,
                              hipStream_t stream) {
  const float* inp = (const float*)d_in[0];
  const int*   edg = (const int*)d_in[1];
  const float* h   = (const float*)d_in[2];
  const float* W   = (const float*)d_in[3];
  const float* b   = (const float*)d_in[4];
  float* out = (float*)d_out;

  const int NH = in_sizes[0];      // N*H
  const int N  = NH / HDIM;
  const int E  = in_sizes[1] / 2;
  const int L  = in_sizes[2] / NH;

  f16* Af   = (f16*)d_ws;               // x-agg / c-agg (blocked, reused)
  f16* Bhf  = Af + (size_t)NH;          // h-agg (blocked)
  f16* zbuf = Bhf + (size_t)NH;         // zpre (linear)
  f16* cbuf = zbuf + (size_t)NH;        // sigmoid(r)*h (blocked gather table)
  f16* xbuf = cbuf + (size_t)NH;        // x f16 (blocked gather table)
  f16* hbuf = xbuf + (size_t)NH;        // h f16 both layers (blocked)
  f16* WT   = hbuf + (size_t)L * NH;    // L*6*H*H transposed f16 weights
  int* deg     = (int*)(WT + (size_t)L * 6 * HDIM * HDIM);
  int* offs    = deg + N;               // N+1
  int* bsum    = offs + (N + 1);        // 256
  int* boff    = bsum + 256;            // 256
  u16* rank    = (u16*)(boff + 256);    // E
  u16* csr_src = rank + (size_t)E;      // E
  // bucket counters: N*16 ints, live only during CSR build -> overlay on Af
  int* cnt     = (int*)Af;

  const int eblocks = (E + 255) / 256;
  const int fblocks = (E + 1023) / 1024;
  const int nsblocks = (N + 255) / 256;
  const int rowblocks = (N + 63) / 64;
  const int p2blocks = ((N + 63) / 64) * 8;
  const int p1blocks = ((N + 127) / 128) * 8;
  const int cvxblocks = (N + 31) / 32;
  const int cvhblocks = (L * N + 31) / 32;
  const int chunk = (N + 255) / 256;    // <=256 requires N<=65536

  // ---- one-time per call: CSR build, transpose, blocked f16 tables ----
  hipMemsetAsync(cnt, 0, (size_t)N * 16 * sizeof(int), stream);
  hipLaunchKernelGGL(degrank_kernel, dim3(eblocks), dim3(256), 0, stream,
                     edg, cnt, rank, E);
  hipLaunchKernelGGL(nodescan_kernel, dim3(nsblocks), dim3(256), 0, stream,
                     cnt, deg, N);
  hipLaunchKernelGGL(scan_part_kernel, dim3(256), dim3(256), 0, stream,
                     deg, bsum, N, chunk);
  hipLaunchKernelGGL(scan_top_kernel, dim3(1), dim3(256), 0, stream,
                     bsum, boff, offs, N);
  hipLaunchKernelGGL(scan_fin_kernel, dim3(256), dim3(256), 0, stream,
                     deg, boff, offs, N, chunk);
  hipLaunchKernelGGL(fill_kernel, dim3(fblocks), dim3(256), 0, stream,
                     edg, offs, cnt, rank, csr_src, E);
  hipLaunchKernelGGL(transw_kernel, dim3(16, L * 6), dim3(256), 0, stream,
                     W, WT);
  hipLaunchKernelGGL(convb_kernel, dim3(cvxblocks), dim3(256), 0, stream,
                     inp, xbuf, N, N);
  hipLaunchKernelGGL(convb_kernel, dim3(cvhblocks), dim3(256), 0, stream,
                     h, hbuf, L * N, L * N);

  for (int i = 0; i < L; ++i) {
    const float* hi = h + (size_t)i * NH;
    const f16* hbl = hbuf + (size_t)i * N * 16;  // layer-i node base (blocked)
    const f16* WTi = WT + (size_t)i * 6 * HDIM * HDIM;
    const float* bi = b + (size_t)i * 6 * HDIM;
    float* outi = out + (size_t)i * NH;

    hipLaunchKernelGGL(pull2_kernel, dim3(p2blocks), dim3(256), 0, stream,
                       csr_src, offs, xbuf, hbl, Af, Bhf, N, L * N);
    hipLaunchKernelGGL(gemm3_kernel, dim3(rowblocks), dim3(256), 0, stream,
                       Af, Bhf, WTi, bi, hbl, zbuf, cbuf, outi, N, L * N);
    hipLaunchKernelGGL(pull1_kernel, dim3(p1blocks), dim3(256), 0, stream,
                       csr_src, offs, cbuf, Af, N);   // Af reused as c-agg
    hipLaunchKernelGGL(gemm_final_kernel, dim3(rowblocks), dim3(256), 0, stream,
                       Af, WTi + (size_t)5 * HDIM * HDIM, bi + 5 * HDIM,
                       zbuf, hi, outi, xbuf, N);
  }
}

// Round 6
// 676.052 us; speedup vs baseline: 1.2537x; 1.1828x over previous
//
#include <hip/hip_runtime.h>
#include <math.h>

#define HDIM 128

typedef _Float16 f16;
typedef unsigned short u16;
typedef __attribute__((ext_vector_type(4))) _Float16 f16x4;
typedef __attribute__((ext_vector_type(8))) _Float16 f16x8;
typedef __attribute__((ext_vector_type(4))) float f32x4;

// ================= CSR build =================
__global__ __launch_bounds__(256) void degrank_kernel(
    const int* __restrict__ edg, int* __restrict__ cnt,
    u16* __restrict__ rank, int E) {
  int e = blockIdx.x * 256 + threadIdx.x;
  if (e < E) {
    int src = edg[e];
    int dst = edg[E + e];
    rank[e] = (u16)atomicAdd(&cnt[dst * 16 + (src >> 12)], 1);
  }
}

__global__ __launch_bounds__(256) void nodescan_kernel(
    int* __restrict__ cnt, int* __restrict__ deg, int N) {
  int node = blockIdx.x * 256 + threadIdx.x;
  if (node >= N) return;
  int* c = cnt + node * 16;
  int s = 0;
  #pragma unroll
  for (int b = 0; b < 16; ++b) {
    int v = c[b];
    c[b] = s;
    s += v;
  }
  deg[node] = s;
}

__global__ __launch_bounds__(256) void scan_part_kernel(
    const int* __restrict__ deg, int* __restrict__ bsum, int n, int chunk) {
  __shared__ int red[256];
  const int b = blockIdx.x, t = threadIdx.x;
  const int begin = b * chunk;
  const int end = min(begin + chunk, n);
  int s = 0;
  for (int i = begin + t; i < end; i += 256) s += deg[i];
  red[t] = s;
  __syncthreads();
  for (int off = 128; off > 0; off >>= 1) {
    if (t < off) red[t] += red[t + off];
    __syncthreads();
  }
  if (t == 0) bsum[b] = red[0];
}

__global__ __launch_bounds__(256) void scan_top_kernel(
    const int* __restrict__ bsum, int* __restrict__ boff,
    int* __restrict__ offs, int n) {
  __shared__ int sh[256];
  const int t = threadIdx.x;
  int v = bsum[t];
  sh[t] = v;
  __syncthreads();
  for (int off = 1; off < 256; off <<= 1) {
    int add = (t >= off) ? sh[t - off] : 0;
    __syncthreads();
    sh[t] += add;
    __syncthreads();
  }
  boff[t] = sh[t] - v;
  if (t == 255) offs[n] = sh[255];
}

__global__ __launch_bounds__(256) void scan_fin_kernel(
    const int* __restrict__ deg, const int* __restrict__ boff,
    int* __restrict__ offs, int n, int chunk) {
  __shared__ int sh[256];
  const int b = blockIdx.x, t = threadIdx.x;
  const int idx = b * chunk + t;
  int v = (t < chunk && idx < n) ? deg[idx] : 0;
  sh[t] = v;
  __syncthreads();
  for (int off = 1; off < 256; off <<= 1) {
    int add = (t >= off) ? sh[t - off] : 0;
    __syncthreads();
    sh[t] += add;
    __syncthreads();
  }
  if (t < chunk && idx < n) offs[idx] = boff[b] + sh[t] - v;
}

__global__ __launch_bounds__(256) void fill_kernel(
    const int* __restrict__ edg, const int* __restrict__ offs,
    const int* __restrict__ cnt, const u16* __restrict__ rank,
    u16* __restrict__ csr_src, int E) {
  int i = blockIdx.x * 256 + threadIdx.x;
  int e0 = i * 4;
  if (e0 >= E) return;
  if (e0 + 4 <= E) {
    int4 s4 = *reinterpret_cast<const int4*>(edg + e0);
    int4 d4 = *reinterpret_cast<const int4*>(edg + E + e0);
    ushort4 r4 = *reinterpret_cast<const ushort4*>(rank + e0);
    csr_src[offs[d4.x] + cnt[d4.x * 16 + (s4.x >> 12)] + r4.x] = (u16)s4.x;
    csr_src[offs[d4.y] + cnt[d4.y * 16 + (s4.y >> 12)] + r4.y] = (u16)s4.y;
    csr_src[offs[d4.z] + cnt[d4.z * 16 + (s4.z >> 12)] + r4.z] = (u16)s4.z;
    csr_src[offs[d4.w] + cnt[d4.w * 16 + (s4.w >> 12)] + r4.w] = (u16)s4.w;
  } else {
    for (int e = e0; e < E; ++e) {
      int src = edg[e];
      int dst = edg[E + e];
      csr_src[offs[dst] + cnt[dst * 16 + (src >> 12)] + rank[e]] = (u16)src;
    }
  }
}

// ===== fp32 [n][128] -> blocked fp16 [4][SN][32] (slice s = cols 32s..32s+31)
// 8 threads per node; sub covers 16 cols -> coalesced 512B row reads.
__global__ __launch_bounds__(256) void convb_kernel(
    const float* __restrict__ src, f16* __restrict__ dst, int n, int SN) {
  const int t = threadIdx.x;
  const int nloc = t >> 3;
  const int sub = t & 7;
  const int sl = sub >> 1;
  const int hf = sub & 1;
  const int node = blockIdx.x * 32 + nloc;
  if (node >= n) return;
  const float* sp = src + (size_t)node * HDIM + sub * 16;
  f16* dp = dst + ((size_t)sl * SN + node) * 32 + hf * 16;
  float4 v0 = *reinterpret_cast<const float4*>(sp + 0);
  float4 v1 = *reinterpret_cast<const float4*>(sp + 4);
  float4 v2 = *reinterpret_cast<const float4*>(sp + 8);
  float4 v3 = *reinterpret_cast<const float4*>(sp + 12);
  f16x8 o0, o1;
  o0[0]=(f16)v0.x; o0[1]=(f16)v0.y; o0[2]=(f16)v0.z; o0[3]=(f16)v0.w;
  o0[4]=(f16)v1.x; o0[5]=(f16)v1.y; o0[6]=(f16)v1.z; o0[7]=(f16)v1.w;
  o1[0]=(f16)v2.x; o1[1]=(f16)v2.y; o1[2]=(f16)v2.z; o1[3]=(f16)v2.w;
  o1[4]=(f16)v3.x; o1[5]=(f16)v3.y; o1[6]=(f16)v3.z; o1[7]=(f16)v3.w;
  *reinterpret_cast<f16x8*>(dp) = o0;
  *reinterpret_cast<f16x8*>(dp + 8) = o1;
}

// ================= W transpose + fp16: WT[gate][n][k] =================
__global__ __launch_bounds__(256) void transw_kernel(
    const float* __restrict__ W, f16* __restrict__ WT) {
  __shared__ float sh[32][33];
  const int g = blockIdx.y;
  const int ti = blockIdx.x >> 2;
  const int tj = blockIdx.x & 3;
  const float* __restrict__ wp = W + (size_t)g * HDIM * HDIM;
  f16* __restrict__ op = WT + (size_t)g * HDIM * HDIM;
  const int t = threadIdx.x;
  #pragma unroll
  for (int it = 0; it < 4; ++it) {
    int elem = it * 256 + t;
    int r = elem >> 5, c = elem & 31;
    sh[r][c] = wp[(size_t)(ti * 32 + r) * HDIM + tj * 32 + c];
  }
  __syncthreads();
  #pragma unroll
  for (int it = 0; it < 4; ++it) {
    int elem = it * 256 + t;
    int cc = elem >> 5, rr = elem & 31;
    op[(size_t)(tj * 32 + cc) * HDIM + ti * 32 + rr] = (f16)sh[rr][cc];
  }
}

// ================= XCD-sliced pull aggregation =================
// class = blockIdx&7 encodes (table = cls>>2, slice = cls&3). Round-robin
// blockIdx->XCD dispatch => each XCD gathers one 3.2MB table slice (L2-fit).
// Node-slice row = 32 f16 = 64B = ONE full cache line; 4 lanes x f16x8.
__global__ __launch_bounds__(256) void pull2_kernel(
    const u16* __restrict__ csr_src, const int* __restrict__ offs,
    const f16* __restrict__ xb, const f16* __restrict__ hbl,
    f16* __restrict__ A, f16* __restrict__ Bh, int N, int hSN) {
  const int cls = blockIdx.x & 7;
  const int tid = cls >> 2;            // 0 = x-table, 1 = h-table
  const int sl = cls & 3;
  const int node = (blockIdx.x >> 3) * 64 + (threadIdx.x >> 2);
  if (node >= N) return;
  const int c8 = (threadIdx.x & 3) << 3;
  const f16* __restrict__ tab =
      tid ? hbl + (size_t)sl * hSN * 32 : xb + (size_t)sl * (size_t)N * 32;
  f16* __restrict__ dst = (tid ? Bh : A) + (size_t)sl * (size_t)N * 32;
  const int s = offs[node];
  const int e = offs[node + 1];
  float acc[8];
  f16x8 sv = *reinterpret_cast<const f16x8*>(tab + (size_t)node * 32 + c8);
  #pragma unroll
  for (int q = 0; q < 8; ++q) acc[q] = (float)sv[q];
  int k = s;
  for (; k + 8 <= e; k += 8) {
    int j0 = csr_src[k];
    int j1 = csr_src[k + 1];
    int j2 = csr_src[k + 2];
    int j3 = csr_src[k + 3];
    int j4 = csr_src[k + 4];
    int j5 = csr_src[k + 5];
    int j6 = csr_src[k + 6];
    int j7 = csr_src[k + 7];
    f16x8 u0 = *reinterpret_cast<const f16x8*>(tab + (size_t)j0 * 32 + c8);
    f16x8 u1 = *reinterpret_cast<const f16x8*>(tab + (size_t)j1 * 32 + c8);
    f16x8 u2 = *reinterpret_cast<const f16x8*>(tab + (size_t)j2 * 32 + c8);
    f16x8 u3 = *reinterpret_cast<const f16x8*>(tab + (size_t)j3 * 32 + c8);
    f16x8 u4 = *reinterpret_cast<const f16x8*>(tab + (size_t)j4 * 32 + c8);
    f16x8 u5 = *reinterpret_cast<const f16x8*>(tab + (size_t)j5 * 32 + c8);
    f16x8 u6 = *reinterpret_cast<const f16x8*>(tab + (size_t)j6 * 32 + c8);
    f16x8 u7 = *reinterpret_cast<const f16x8*>(tab + (size_t)j7 * 32 + c8);
    #pragma unroll
    for (int q = 0; q < 8; ++q)
      acc[q] += (((float)u0[q] + (float)u1[q]) + ((float)u2[q] + (float)u3[q])) +
                (((float)u4[q] + (float)u5[q]) + ((float)u6[q] + (float)u7[q]));
  }
  for (; k < e; ++k) {
    f16x8 u = *reinterpret_cast<const f16x8*>(tab + (size_t)csr_src[k] * 32 + c8);
    #pragma unroll
    for (int q = 0; q < 8; ++q) acc[q] += (float)u[q];
  }
  f16x8 o;
  #pragma unroll
  for (int q = 0; q < 8; ++q) o[q] = (f16)acc[q];
  *reinterpret_cast<f16x8*>(dst + (size_t)node * 32 + c8) = o;
}

// single-table sliced pull: class = blockIdx&3 (slice); 64 nodes x 4 lanes
__global__ __launch_bounds__(256) void pull1_kernel(
    const u16* __restrict__ csr_src, const int* __restrict__ offs,
    const f16* __restrict__ cb, f16* __restrict__ Ctot, int N) {
  const int sl = blockIdx.x & 3;
  const int node = (blockIdx.x >> 2) * 64 + (threadIdx.x >> 2);
  if (node >= N) return;
  const int c8 = (threadIdx.x & 3) << 3;
  const f16* __restrict__ tab = cb + (size_t)sl * (size_t)N * 32;
  f16* __restrict__ dst = Ctot + (size_t)sl * (size_t)N * 32;
  const int s = offs[node];
  const int e = offs[node + 1];
  float acc[8];
  f16x8 sv = *reinterpret_cast<const f16x8*>(tab + (size_t)node * 32 + c8);
  #pragma unroll
  for (int q = 0; q < 8; ++q) acc[q] = (float)sv[q];
  int k = s;
  for (; k + 8 <= e; k += 8) {
    int j0 = csr_src[k];
    int j1 = csr_src[k + 1];
    int j2 = csr_src[k + 2];
    int j3 = csr_src[k + 3];
    int j4 = csr_src[k + 4];
    int j5 = csr_src[k + 5];
    int j6 = csr_src[k + 6];
    int j7 = csr_src[k + 7];
    f16x8 u0 = *reinterpret_cast<const f16x8*>(tab + (size_t)j0 * 32 + c8);
    f16x8 u1 = *reinterpret_cast<const f16x8*>(tab + (size_t)j1 * 32 + c8);
    f16x8 u2 = *reinterpret_cast<const f16x8*>(tab + (size_t)j2 * 32 + c8);
    f16x8 u3 = *reinterpret_cast<const f16x8*>(tab + (size_t)j3 * 32 + c8);
    f16x8 u4 = *reinterpret_cast<const f16x8*>(tab + (size_t)j4 * 32 + c8);
    f16x8 u5 = *reinterpret_cast<const f16x8*>(tab + (size_t)j5 * 32 + c8);
    f16x8 u6 = *reinterpret_cast<const f16x8*>(tab + (size_t)j6 * 32 + c8);
    f16x8 u7 = *reinterpret_cast<const f16x8*>(tab + (size_t)j7 * 32 + c8);
    #pragma unroll
    for (int q = 0; q < 8; ++q)
      acc[q] += (((float)u0[q] + (float)u1[q]) + ((float)u2[q] + (float)u3[q])) +
                (((float)u4[q] + (float)u5[q]) + ((float)u6[q] + (float)u7[q]));
  }
  for (; k < e; ++k) {
    f16x8 u = *reinterpret_cast<const f16x8*>(tab + (size_t)csr_src[k] * 32 + c8);
    #pragma unroll
    for (int q = 0; q < 8; ++q) acc[q] += (float)u[q];
  }
  f16x8 o;
  #pragma unroll
  for (int q = 0; q < 8; ++q) o[q] = (f16)acc[q];
  *reinterpret_cast<f16x8*>(dst + (size_t)node * 32 + c8) = o;
}

// ========== LDS staging from blocked [4][SN][32] layout ==========
// 16 consecutive threads assemble one contiguous 256B As row -> no LDS
// write conflicts; global reads are 64B segments.
__device__ __forceinline__ void stage_blocked(
    const f16* __restrict__ src, f16* __restrict__ As,
    int row0, int N, int SN, int t) {
  #pragma unroll
  for (int i = 0; i < 4; ++i) {
    int u = i * 256 + t;          // 1024 chunks of 16B
    int row = u >> 4;
    int sl = (u >> 2) & 3;
    int ck = u & 3;
    int r = row0 + row;
    f16x8 v{};
    if (r < N) v = *reinterpret_cast<const f16x8*>(
        src + ((size_t)sl * SN + r) * 32 + ck * 8);
    *reinterpret_cast<f16x8*>(&As[row * 136 + sl * 32 + ck * 8]) = v;
  }
}

__device__ __forceinline__ void mfma_tile(
    const f16* As, const f16* Ws, int wr, int wc, int ln15, int quad,
    f32x4 (&acc)[2][4]) {
  #pragma unroll
  for (int s = 0; s < 4; ++s) {
    f16x8 a0 = *reinterpret_cast<const f16x8*>(
        &As[(wr * 32 + ln15) * 136 + s * 32 + quad * 8]);
    f16x8 a1 = *reinterpret_cast<const f16x8*>(
        &As[(wr * 32 + 16 + ln15) * 136 + s * 32 + quad * 8]);
    #pragma unroll
    for (int ni = 0; ni < 4; ++ni) {
      f16x8 bf = *reinterpret_cast<const f16x8*>(
          &Ws[(wc * 64 + ni * 16 + ln15) * 136 + s * 32 + quad * 8]);
      acc[0][ni] = __builtin_amdgcn_mfma_f32_16x16x32_f16(a0, bf, acc[0][ni], 0, 0, 0);
      acc[1][ni] = __builtin_amdgcn_mfma_f32_16x16x32_f16(a1, bf, acc[1][ni], 0, 0, 0);
    }
  }
}

// ============ fused gate GEMM (z, r, h-partial in one pass) ========
__global__ __launch_bounds__(256, 3) void gemm3_kernel(
    const f16* __restrict__ A, const f16* __restrict__ Bh,
    const f16* __restrict__ WT, const float* __restrict__ b,
    const f16* __restrict__ hbl, f16* __restrict__ zb,
    f16* __restrict__ cb, float* __restrict__ hpre, int N, int hSN) {
  __shared__ f16 As[64 * 136];
  __shared__ f16 Ws[128 * 136];
  const int t = threadIdx.x;
  const int w = t >> 6, wr = w >> 1, wc = w & 1;
  const int lane = t & 63, ln15 = lane & 15, quad = lane >> 4;
  const int row0 = blockIdx.x * 64;
  f32x4 accZ[2][4], accR[2][4], accH[2][4];
  #pragma unroll
  for (int i = 0; i < 2; ++i)
    #pragma unroll
    for (int j = 0; j < 4; ++j) {
      accZ[i][j] = (f32x4){0.f, 0.f, 0.f, 0.f};
      accR[i][j] = (f32x4){0.f, 0.f, 0.f, 0.f};
      accH[i][j] = (f32x4){0.f, 0.f, 0.f, 0.f};
    }

  stage_blocked(A, As, row0, N, N, t);
  #pragma unroll
  for (int g = 0; g < 3; ++g) {          // gates 0,2,4 vs x-aggregate
    const f16* __restrict__ wp = WT + (size_t)(g * 2) * HDIM * HDIM;
    __syncthreads();
    #pragma unroll
    for (int i = 0; i < 8; ++i) {
      int flat = i * 256 + t;
      int n = flat >> 4;
      int o = (flat & 15) * 8;
      *reinterpret_cast<f16x8*>(&Ws[n * 136 + o]) =
          *reinterpret_cast<const f16x8*>(wp + (size_t)n * HDIM + o);
    }
    __syncthreads();
    if (g == 0) mfma_tile(As, Ws, wr, wc, ln15, quad, accZ);
    else if (g == 1) mfma_tile(As, Ws, wr, wc, ln15, quad, accR);
    else mfma_tile(As, Ws, wr, wc, ln15, quad, accH);
  }
  __syncthreads();
  stage_blocked(Bh, As, row0, N, N, t);
  #pragma unroll
  for (int g = 0; g < 2; ++g) {          // gates 1,3 vs h-aggregate
    const f16* __restrict__ wp = WT + (size_t)(g * 2 + 1) * HDIM * HDIM;
    __syncthreads();
    #pragma unroll
    for (int i = 0; i < 8; ++i) {
      int flat = i * 256 + t;
      int n = flat >> 4;
      int o = (flat & 15) * 8;
      *reinterpret_cast<f16x8*>(&Ws[n * 136 + o]) =
          *reinterpret_cast<const f16x8*>(wp + (size_t)n * HDIM + o);
    }
    __syncthreads();
    if (g == 0) mfma_tile(As, Ws, wr, wc, ln15, quad, accZ);
    else mfma_tile(As, Ws, wr, wc, ln15, quad, accR);
  }

  // ---- epilogue: zpre (linear), c=sigmoid(r)*h (blocked), hpre (linear) ----
  #pragma unroll
  for (int ni = 0; ni < 4; ++ni) {
    const int col = wc * 64 + ni * 16 + ln15;
    const int slc = col >> 5;
    const int cw = col & 31;
    float bz = b[0 * HDIM + col] + b[1 * HDIM + col];
    float br = b[2 * HDIM + col] + b[3 * HDIM + col];
    float bh = b[4 * HDIM + col];
    #pragma unroll
    for (int mi = 0; mi < 2; ++mi) {
      #pragma unroll
      for (int r = 0; r < 4; ++r) {
        int row = row0 + wr * 32 + mi * 16 + quad * 4 + r;
        if (row >= N) continue;
        size_t idx = (size_t)row * HDIM + col;
        zb[idx] = (f16)(accZ[mi][ni][r] + bz);
        float rv = accR[mi][ni][r] + br;
        float rg = 1.f / (1.f + expf(-rv));
        float hv = (float)hbl[((size_t)slc * hSN + row) * 32 + cw];
        cb[((size_t)slc * N + row) * 32 + cw] = (f16)(rg * hv);
        hpre[idx] = accH[mi][ni][r] + bh;
      }
    }
  }
}

// ============ final GEMM + GRU combine =======================
__global__ __launch_bounds__(256, 3) void gemm_final_kernel(
    const f16* __restrict__ Ctot, const f16* __restrict__ WT5,
    const float* __restrict__ b5, const f16* __restrict__ zb,
    const float* __restrict__ hi, float* __restrict__ outi,
    f16* __restrict__ xb, int N) {
  __shared__ f16 As[64 * 136];
  __shared__ f16 Ws[128 * 136];
  const int t = threadIdx.x;
  const int w = t >> 6, wr = w >> 1, wc = w & 1;
  const int lane = t & 63, ln15 = lane & 15, quad = lane >> 4;
  const int row0 = blockIdx.x * 64;
  f32x4 acc[2][4];
  #pragma unroll
  for (int i = 0; i < 2; ++i)
    #pragma unroll
    for (int j = 0; j < 4; ++j) acc[i][j] = (f32x4){0.f, 0.f, 0.f, 0.f};

  stage_blocked(Ctot, As, row0, N, N, t);
  #pragma unroll
  for (int i = 0; i < 8; ++i) {
    int flat = i * 256 + t;
    int n = flat >> 4;
    int o = (flat & 15) * 8;
    *reinterpret_cast<f16x8*>(&Ws[n * 136 + o]) =
        *reinterpret_cast<const f16x8*>(WT5 + (size_t)n * HDIM + o);
  }
  __syncthreads();
  mfma_tile(As, Ws, wr, wc, ln15, quad, acc);

  #pragma unroll
  for (int ni = 0; ni < 4; ++ni) {
    const int col = wc * 64 + ni * 16 + ln15;
    const int slc = col >> 5;
    const int cw = col & 31;
    float bias = b5[col];
    #pragma unroll
    for (int mi = 0; mi < 2; ++mi) {
      #pragma unroll
      for (int r = 0; r < 4; ++r) {
        int row = row0 + wr * 32 + mi * 16 + quad * 4 + r;
        if (row >= N) continue;
        size_t idx = (size_t)row * HDIM + col;
        float v = acc[mi][ni][r] + bias + outi[idx];  // + hpre
        float ht = tanhf(v);
        float z = 1.f / (1.f + expf(-(float)zb[idx]));
        float o = z * hi[idx] + (1.f - z) * ht;
        outi[idx] = o;
        xb[((size_t)slc * N + row) * 32 + cw] = (f16)o;  // blocked x table
      }
    }
  }
}

extern "C" void kernel_launch(void* const* d_in, const int* in_sizes, int n_in,
                              void* d_out, int out_size, void* d_ws, size_t ws_size,
                              hipStream_t stream) {
  const float* inp = (const float*)d_in[0];
  const int*   edg = (const int*)d_in[1];
  const float* h   = (const float*)d_in[2];
  const float* W   = (const float*)d_in[3];
  const float* b   = (const float*)d_in[4];
  float* out = (float*)d_out;

  const int NH = in_sizes[0];      // N*H
  const int N  = NH / HDIM;
  const int E  = in_sizes[1] / 2;
  const int L  = in_sizes[2] / NH;

  f16* Af   = (f16*)d_ws;               // x-agg / c-agg (blocked, reused)
  f16* Bhf  = Af + (size_t)NH;          // h-agg (blocked)
  f16* zbuf = Bhf + (size_t)NH;         // zpre (linear)
  f16* cbuf = zbuf + (size_t)NH;        // sigmoid(r)*h (blocked gather table)
  f16* xbuf = cbuf + (size_t)NH;        // x f16 (blocked gather table)
  f16* hbuf = xbuf + (size_t)NH;        // h f16 both layers (blocked)
  f16* WT   = hbuf + (size_t)L * NH;    // L*6*H*H transposed f16 weights
  int* deg     = (int*)(WT + (size_t)L * 6 * HDIM * HDIM);
  int* offs    = deg + N;               // N+1
  int* bsum    = offs + (N + 1);        // 256
  int* boff    = bsum + 256;            // 256
  u16* rank    = (u16*)(boff + 256);    // E
  u16* csr_src = rank + (size_t)E;      // E
  // bucket counters: N*16 ints, live only during CSR build -> overlay on Af
  int* cnt     = (int*)Af;

  const int eblocks = (E + 255) / 256;
  const int fblocks = (E + 1023) / 1024;
  const int nsblocks = (N + 255) / 256;
  const int rowblocks = (N + 63) / 64;
  const int p2blocks = ((N + 63) / 64) * 8;
  const int p1blocks = ((N + 63) / 64) * 4;
  const int cvxblocks = (N + 31) / 32;
  const int cvhblocks = (L * N + 31) / 32;
  const int chunk = (N + 255) / 256;    // <=256 requires N<=65536

  // ---- one-time per call: CSR build, transpose, blocked f16 tables ----
  hipMemsetAsync(cnt, 0, (size_t)N * 16 * sizeof(int), stream);
  hipLaunchKernelGGL(degrank_kernel, dim3(eblocks), dim3(256), 0, stream,
                     edg, cnt, rank, E);
  hipLaunchKernelGGL(nodescan_kernel, dim3(nsblocks), dim3(256), 0, stream,
                     cnt, deg, N);
  hipLaunchKernelGGL(scan_part_kernel, dim3(256), dim3(256), 0, stream,
                     deg, bsum, N, chunk);
  hipLaunchKernelGGL(scan_top_kernel, dim3(1), dim3(256), 0, stream,
                     bsum, boff, offs, N);
  hipLaunchKernelGGL(scan_fin_kernel, dim3(256), dim3(256), 0, stream,
                     deg, boff, offs, N, chunk);
  hipLaunchKernelGGL(fill_kernel, dim3(fblocks), dim3(256), 0, stream,
                     edg, offs, cnt, rank, csr_src, E);
  hipLaunchKernelGGL(transw_kernel, dim3(16, L * 6), dim3(256), 0, stream,
                     W, WT);
  hipLaunchKernelGGL(convb_kernel, dim3(cvxblocks), dim3(256), 0, stream,
                     inp, xbuf, N, N);
  hipLaunchKernelGGL(convb_kernel, dim3(cvhblocks), dim3(256), 0, stream,
                     h, hbuf, L * N, L * N);

  for (int i = 0; i < L; ++i) {
    const float* hi = h + (size_t)i * NH;
    const f16* hbl = hbuf + (size_t)i * N * 32;  // layer-i base (blocked)
    const f16* WTi = WT + (size_t)i * 6 * HDIM * HDIM;
    const float* bi = b + (size_t)i * 6 * HDIM;
    float* outi = out + (size_t)i * NH;

    hipLaunchKernelGGL(pull2_kernel, dim3(p2blocks), dim3(256), 0, stream,
                       csr_src, offs, xbuf, hbl, Af, Bhf, N, L * N);
    hipLaunchKernelGGL(gemm3_kernel, dim3(rowblocks), dim3(256), 0, stream,
                       Af, Bhf, WTi, bi, hbl, zbuf, cbuf, outi, N, L * N);
    hipLaunchKernelGGL(pull1_kernel, dim3(p1blocks), dim3(256), 0, stream,
                       csr_src, offs, cbuf, Af, N);   // Af reused as c-agg
    hipLaunchKernelGGL(gemm_final_kernel, dim3(rowblocks), dim3(256), 0, stream,
                       Af, WTi + (size_t)5 * HDIM * HDIM, bi + 5 * HDIM,
                       zbuf, hi, outi, xbuf, N);
  }
}